// Round 3
// baseline (2997.972 us; speedup 1.0000x reference)
//
#include <hip/hip_runtime.h>
#include <hip/hip_bf16.h>
#include <math.h>

#define BATCH 8
#define CH 64
#define HH 256
#define WW 256
#define HID 512
#define NE 4

typedef short v8s __attribute__((ext_vector_type(8)));
typedef float v4f __attribute__((ext_vector_type(4)));
typedef float v16f __attribute__((ext_vector_type(16)));

static __device__ __forceinline__ unsigned short f2bf(float v) {
    __hip_bfloat16 h = __float2bfloat16(v);
    return *(unsigned short*)&h;
}

// ---------------- K1: per-(b,c) spatial mean -> g[8*64] ----------------
__global__ __launch_bounds__(256) void mean_kernel(const float* __restrict__ x,
                                                   float* __restrict__ g) {
    int bc = blockIdx.x;
    const float* p = x + (size_t)bc * (HH * WW);
    float s = 0.f;
    for (int i = threadIdx.x; i < HH * WW; i += 256) s += p[i];
    __shared__ float red[256];
    red[threadIdx.x] = s;
    __syncthreads();
    for (int off = 128; off > 0; off >>= 1) {
        if (threadIdx.x < off) red[threadIdx.x] += red[threadIdx.x + off];
        __syncthreads();
    }
    if (threadIdx.x == 0) g[bc] = red[0] * (1.0f / (HH * WW));
}

// ---------------- K2: gating MLP + softmax + top2 + coef + loss --------
__global__ __launch_bounds__(512) void gate_kernel(const float* __restrict__ g,
                                                   const float* __restrict__ gw1,
                                                   const float* __restrict__ gb1,
                                                   const float* __restrict__ gw2,
                                                   const float* __restrict__ gb2,
                                                   float* __restrict__ coef_out,
                                                   float* __restrict__ loss_out) {
    __shared__ float h[BATCH][HID];
    __shared__ float logits[BATCH][NE];
    int t = threadIdx.x;
    for (int b = 0; b < BATCH; b++) {
        float acc = gb1[t];
        for (int c = 0; c < CH; c++) acc = fmaf(g[b * CH + c], gw1[t * CH + c], acc);
        h[b][t] = fmaxf(acc, 0.f);
    }
    __syncthreads();
    if (t < BATCH * NE) {
        int b = t / NE, e = t % NE;
        float acc = gb2[e];
        for (int j = 0; j < HID; j++) acc = fmaf(h[b][j], gw2[e * HID + j], acc);
        logits[b][e] = acc;
    }
    __syncthreads();
    if (t == 0) {
        float sm[BATCH][NE];
        for (int b = 0; b < BATCH; b++) {
            float m = logits[b][0];
            for (int e = 1; e < NE; e++) m = fmaxf(m, logits[b][e]);
            float s = 0.f;
            for (int e = 0; e < NE; e++) { sm[b][e] = expf(logits[b][e] - m); s += sm[b][e]; }
            for (int e = 0; e < NE; e++) sm[b][e] /= s;
        }
        float mean = 0.f;
        for (int b = 0; b < BATCH; b++)
            for (int e = 0; e < NE; e++) mean += sm[b][e];
        mean *= 1.0f / (BATCH * NE);
        float var = 0.f;
        for (int b = 0; b < BATCH; b++)
            for (int e = 0; e < NE; e++) {
                float d = sm[b][e] - mean;
                var += d * d;
            }
        var *= 1.0f / (BATCH * NE - 1);
        *loss_out = sqrtf(var) / (mean + 1e-10f) * 0.1f;
        float coef[NE] = {0.f, 0.f, 0.f, 0.f};
        for (int b = 0; b < BATCH; b++) {
            int i0 = 0;
            for (int e = 1; e < NE; e++)
                if (sm[b][e] > sm[b][i0]) i0 = e;
            int i1 = -1;
            for (int e = 0; e < NE; e++) {
                if (e == i0) continue;
                if (i1 < 0 || sm[b][e] > sm[b][i1]) i1 = e;
            }
            float v0 = sm[b][i0], v1 = sm[b][i1];
            float be = expf(v1 - v0);
            float a0 = 1.f / (1.f + be);
            float a1 = be / (1.f + be);
            coef[i0] += a0;
            coef[i1] += a1;
        }
        for (int e = 0; e < NE; e++) coef_out[e] = coef[e];
    }
}

// ---------------- K3a: weights OIHW fp32 -> wT[e][tap][co][ci] bf16 ----
__global__ __launch_bounds__(256) void wtrans_kernel(const float* __restrict__ ew1,
                                                     const float* __restrict__ ew3,
                                                     const float* __restrict__ ew7,
                                                     const float* __restrict__ ew11,
                                                     unsigned short* __restrict__ wT) {
    int gid = blockIdx.x * 256 + threadIdx.x;  // < 180*512 = 92160
    int tapg = gid >> 9;
    int rem = gid & 511;
    int co = rem >> 3, kg = rem & 7;
    const float* src;
    int k, tap, dstbase;
    if (tapg < 1) { src = ew1; k = 1; tap = tapg; dstbase = 0; }
    else if (tapg < 10) { src = ew3; k = 3; tap = tapg - 1; dstbase = 1 * 4096; }
    else if (tapg < 59) { src = ew7; k = 7; tap = tapg - 10; dstbase = 10 * 4096; }
    else { src = ew11; k = 11; tap = tapg - 59; dstbase = 59 * 4096; }
    int ky = tap / k, kx = tap - ky * k;
    unsigned short o[8];
#pragma unroll
    for (int j = 0; j < 8; j++) {
        int ci = kg * 8 + j;
        o[j] = f2bf(src[((co * 64 + ci) * k + ky) * k + kx]);
    }
    *(v8s*)(wT + (size_t)dstbase + ((size_t)tap * 64 + co) * 64 + kg * 8) = *(v8s*)o;
}

// ---------------- K3b: x NCHW fp32 -> xT[b][y][x][ci] bf16 -------------
#define XP 258
__global__ __launch_bounds__(256) void xtrans_kernel(const float* __restrict__ x,
                                                     unsigned short* __restrict__ xT) {
    __shared__ unsigned short t[64 * XP];
    int blk = blockIdx.x;  // b*256 + y
    int b = blk >> 8, y = blk & 255;
    int tid = threadIdx.x;
    for (int ci = 0; ci < 64; ci++) {
        float v = x[((size_t)(b * 64 + ci)) * 65536 + (size_t)y * 256 + tid];
        t[ci * XP + tid] = f2bf(v);
    }
    __syncthreads();
    unsigned short* dst = xT + (size_t)blk * 256 * 64;
    for (int c = tid; c < 2048; c += 256) {
        int xx = c >> 3, kg = c & 7;
        unsigned short o[8];
#pragma unroll
        for (int j = 0; j < 8; j++) o[j] = t[(kg * 8 + j) * XP + xx];
        *(v8s*)(dst + (size_t)xx * 64 + kg * 8) = *(v8s*)o;
    }
}

// ---------------- K4: 32x32x16 MFMA expert-sequential fused conv -------
// block = (b, ytile16, xtile8): 16x8 px, 64 co. 4 waves; wave w = rows
// [w*4, w*4+4) x 8 cols = 32 px (MFMA m), all 64 co = 2 n-tiles.
// LDS halo: 26 rows x 18 cols x 64 ci bf16 = 59904 B, 128 B/px, 3-bit XOR
// swizzle: 16B chunk c of pixel px stored at quad c ^ (px&7).
//
// R3 CHANGE: COMPACT CODE. The previous version fully unrolled all 180
// taps (~5-6K instrs, ~45KB straight-line code executed once per wave) ->
// I$ streaming misses dominated (~2280 cy/tap observed vs ~260 modeled).
// Now: runtime dy loop x software-pipelined dx pair-loop (unroll-by-2 for
// static register parity), 1-tap lookahead double buffer. Hot code ~2KB.
__device__ __forceinline__ v16f mfma32(v8s a, v8s b, v16f c) {
    return __builtin_amdgcn_mfma_f32_32x32x16_bf16(a, b, c, 0, 0, 0);
}

// A-fragment load: pixel px, 4 k-slices. addr = px*128 + ((khx^q4)^(kc<<5))
#define LDA(A, sxb, pxv, khx)                                   \
    {                                                           \
        int _px = (pxv);                                        \
        const char* _ap = (sxb) + _px * 128;                    \
        int _o0 = (khx) ^ ((_px & 7) << 4);                     \
        A[0] = *(const v8s*)(_ap + _o0);                        \
        A[1] = *(const v8s*)(_ap + (_o0 ^ 32));                 \
        A[2] = *(const v8s*)(_ap + (_o0 ^ 64));                 \
        A[3] = *(const v8s*)(_ap + (_o0 ^ 96));                 \
    }

// B-fragment load: one tap's [co][ci] block at wp (8192 B), 2 n-tiles.
#define LDB(B, wp, b0, b1)                                      \
    {                                                           \
        const char* _wp = (wp);                                 \
        B[0] = *(const v8s*)(_wp + (b0));                       \
        B[1] = *(const v8s*)(_wp + (b0) + 32);                  \
        B[2] = *(const v8s*)(_wp + (b0) + 64);                  \
        B[3] = *(const v8s*)(_wp + (b0) + 96);                  \
        B[4] = *(const v8s*)(_wp + (b1));                       \
        B[5] = *(const v8s*)(_wp + (b1) + 32);                  \
        B[6] = *(const v8s*)(_wp + (b1) + 64);                  \
        B[7] = *(const v8s*)(_wp + (b1) + 96);                  \
    }

#define MM(A, B)                                                \
    {                                                           \
        a0 = mfma32(A[0], B[0], a0);                            \
        a1 = mfma32(A[0], B[4], a1);                            \
        a0 = mfma32(A[1], B[1], a0);                            \
        a1 = mfma32(A[1], B[5], a1);                            \
        a0 = mfma32(A[2], B[2], a0);                            \
        a1 = mfma32(A[2], B[6], a1);                            \
        a0 = mfma32(A[3], B[3], a0);                            \
        a1 = mfma32(A[3], B[7], a1);                            \
    }

template <int KS, int OFF, int CIDX>
__device__ __forceinline__ void expert_pass(const unsigned short* sx,
                                            const unsigned short* wTe,
                                            const float* __restrict__ eb,
                                            const float* __restrict__ coef,
                                            int p00, int khx, int n,
                                            int boffB0, int boffB1,
                                            v16f& mix0, v16f& mix1) {
    v16f a0 = {};
    v16f a1 = {};
    const int pD = p00 + OFF * 19;   // halo px at (dy=0,dx=0) of this expert
    const char* sxb = (const char*)sx;
    const char* wp = (const char*)wTe;  // advances 8192 B per tap (tap = dy*KS+dx)
#pragma unroll 1
    for (int dy = 0; dy < KS; ++dy) {
        int px = pD + 18 * dy;
        v8s A0[4], A1[4], B0[8], B1[8];
        LDA(A0, sxb, px, khx);
        LDB(B0, wp, boffB0, boffB1);
#pragma unroll 1
        for (int i = 0; i < (KS - 1) / 2; ++i) {
            // prefetch tap dx+1 while MFMAing tap dx, then swap
            LDA(A1, sxb, px + 1, khx);
            LDB(B1, wp + 8192, boffB0, boffB1);
            MM(A0, B0);
            LDA(A0, sxb, px + 2, khx);
            LDB(B0, wp + 16384, boffB0, boffB1);
            MM(A1, B1);
            px += 2;
            wp += 16384;
        }
        MM(A0, B0);   // last tap of the row (dx = KS-1)
        wp += 8192;
    }
    // fold this expert into the mix: mix += coef * sigmoid(acc + bias)
    float ce = coef[CIDX];
    float b0v = eb[n];
    float b1v = eb[32 + n];
#pragma unroll
    for (int r = 0; r < 16; ++r) {
        float z0 = a0[r] + b0v;
        float z1 = a1[r] + b1v;
        mix0[r] = fmaf(ce, 1.f / (1.f + __expf(-z0)), mix0[r]);
        mix1[r] = fmaf(ce, 1.f / (1.f + __expf(-z1)), mix1[r]);
    }
}

__global__ __launch_bounds__(256, 2) void moe32_kernel(
        const unsigned short* __restrict__ xT, const unsigned short* __restrict__ wT,
        const float* __restrict__ x,
        const float* __restrict__ eb1, const float* __restrict__ eb3,
        const float* __restrict__ eb7, const float* __restrict__ eb11,
        const float* __restrict__ coef, float* __restrict__ out) {
    __shared__ unsigned short sx[26 * 18 * 64];  // 59904 B
    int blk = blockIdx.x;
    int xt = blk & 31, yt = (blk >> 5) & 15, b = blk >> 9;
    int x0 = xt * 8, y0 = yt * 16;
    int tid = threadIdx.x;

    // ---- stage swizzled halo: chunk c of px stored at quad c ^ (px&7) ----
    for (int i = tid; i < 3744; i += 256) {
        int hrow = i / 144;
        int rem = i - hrow * 144;
        int hcol = rem >> 3, c = rem & 7;
        int px = hrow * 18 + hcol;
        int gy = y0 + hrow - 5, gx = x0 + hcol - 5;
        v8s v = {0, 0, 0, 0, 0, 0, 0, 0};
        if ((unsigned)gy < 256u && (unsigned)gx < 256u)
            v = *(const v8s*)(xT + (((size_t)(b * 256 + gy) * 256 + gx) * 64 + c * 8));
        int cs = c ^ (px & 7);
        *(v8s*)(sx + px * 64 + cs * 8) = v;
    }
    __syncthreads();

    int lane = tid & 63, w = tid >> 6;
    int kh = lane >> 5, n = lane & 31;
    int prow = (lane & 31) >> 3, pcol = lane & 7;
    int p00 = (w * 4 + prow) * 18 + pcol;  // halo px of this lane's pixel at tap origin
    int khx = kh << 4;
    int boffB0 = n * 128 + kh * 16;        // bytes into a tap's [co][ci] block
    int boffB1 = (32 + n) * 128 + kh * 16;

    v16f mix0 = {};
    v16f mix1 = {};

    const unsigned short* wT1 = wT;
    const unsigned short* wT3 = wT + 4096;
    const unsigned short* wT7 = wT + 10 * 4096;
    const unsigned short* wT11 = wT + 59 * 4096;

    expert_pass<11, 0, 3>(sx, wT11, eb11, coef, p00, khx, n, boffB0, boffB1, mix0, mix1);
    expert_pass<7, 2, 2>(sx, wT7, eb7, coef, p00, khx, n, boffB0, boffB1, mix0, mix1);
    expert_pass<3, 4, 1>(sx, wT3, eb3, coef, p00, khx, n, boffB0, boffB1, mix0, mix1);
    expert_pass<1, 5, 0>(sx, wT1, eb1, coef, p00, khx, n, boffB0, boffB1, mix0, mix1);

    // ---- final: out = x * mix ----
    size_t pb0 = ((size_t)(b * 64 + n)) * 65536;
    size_t pb1 = ((size_t)(b * 64 + 32 + n)) * 65536;
    int yb = y0 + w * 4, xb = x0 + kh * 4;
#pragma unroll
    for (int g = 0; g < 4; ++g) {
        size_t off = (size_t)(yb + g) * 256 + xb;
        v4f xv0 = *(const v4f*)(x + pb0 + off);
        v4f xv1 = *(const v4f*)(x + pb1 + off);
        v4f o0, o1;
#pragma unroll
        for (int r = 0; r < 4; ++r) {
            o0[r] = xv0[r] * mix0[g * 4 + r];
            o1[r] = xv1[r] * mix1[g * 4 + r];
        }
        *(v4f*)(out + pb0 + off) = o0;
        *(v4f*)(out + pb1 + off) = o1;
    }
}

// ---------------- fallback direct conv (R1, verified) ------------------
__global__ __launch_bounds__(256) void conv_kernel(const float* __restrict__ x,
                                                   const float* __restrict__ ew1,
                                                   const float* __restrict__ eb1,
                                                   const float* __restrict__ ew3,
                                                   const float* __restrict__ eb3,
                                                   const float* __restrict__ ew7,
                                                   const float* __restrict__ eb7,
                                                   const float* __restrict__ ew11,
                                                   const float* __restrict__ eb11,
                                                   const float* __restrict__ coef,
                                                   float* __restrict__ out) {
    int blk = blockIdx.x;
    int y = blk & (HH - 1);
    int c = (blk >> 8) & (CH - 1);
    int b = blk >> 14;
    int xi = threadIdx.x;
    const size_t plane = (size_t)HH * WW;
    float a0 = 0.f, a1 = 0.f, a2 = 0.f, a3 = 0.f;
    for (int dy = 0; dy < 11; dy++) {
        int yy = y + dy - 5;
        if (yy < 0 || yy >= HH) continue;
        bool in7y = (dy >= 2 && dy <= 8);
        bool in3y = (dy >= 4 && dy <= 6);
        bool in1y = (dy == 5);
        for (int ci = 0; ci < CH; ci++) {
            const float* xrow = x + ((size_t)(b * CH + ci)) * plane + (size_t)yy * WW;
            const float* w11row = ew11 + (((c * CH + ci) * 11 + dy) * 11);
            const float* w7row = in7y ? (ew7 + (((c * CH + ci) * 7 + (dy - 2)) * 7)) : ew7;
            const float* w3row = in3y ? (ew3 + (((c * CH + ci) * 3 + (dy - 4)) * 3)) : ew3;
            float w1v = in1y ? ew1[c * CH + ci] : 0.f;
#pragma unroll
            for (int dx = 0; dx < 11; dx++) {
                int xc = xi + dx - 5;
                float xv = (xc >= 0 && xc < WW) ? xrow[xc] : 0.f;
                a3 = fmaf(w11row[dx], xv, a3);
                if (dx >= 2 && dx <= 8) { if (in7y) a2 = fmaf(w7row[dx - 2], xv, a2); }
                if (dx >= 4 && dx <= 6) { if (in3y) a1 = fmaf(w3row[dx - 4], xv, a1); }
                if (dx == 5) { if (in1y) a0 = fmaf(w1v, xv, a0); }
            }
        }
    }
    a0 += eb1[c]; a1 += eb3[c]; a2 += eb7[c]; a3 += eb11[c];
    float s0 = 1.f / (1.f + expf(-a0));
    float s1 = 1.f / (1.f + expf(-a1));
    float s2 = 1.f / (1.f + expf(-a2));
    float s3 = 1.f / (1.f + expf(-a3));
    float mix = coef[0] * s0 + coef[1] * s1 + coef[2] * s2 + coef[3] * s3;
    size_t idx = ((size_t)(b * CH + c)) * plane + (size_t)y * WW + xi;
    out[idx] = x[idx] * mix;
}

extern "C" void kernel_launch(void* const* d_in, const int* in_sizes, int n_in,
                              void* d_out, int out_size, void* d_ws, size_t ws_size,
                              hipStream_t stream) {
    const float* x = (const float*)d_in[0];
    const float* gw1 = (const float*)d_in[1];
    const float* gb1 = (const float*)d_in[2];
    const float* gw2 = (const float*)d_in[3];
    const float* gb2 = (const float*)d_in[4];
    const float* ew1 = (const float*)d_in[5];
    const float* eb1 = (const float*)d_in[6];
    const float* ew3 = (const float*)d_in[7];
    const float* eb3 = (const float*)d_in[8];
    const float* ew7 = (const float*)d_in[9];
    const float* eb7 = (const float*)d_in[10];
    const float* ew11 = (const float*)d_in[11];
    const float* eb11 = (const float*)d_in[12];

    float* out = (float*)d_out;
    float* wsf = (float*)d_ws;
    float* g = wsf;                                // 512 floats
    float* coef = wsf + 512;                       // 4 floats (+pad to 520)
    unsigned short* wT = (unsigned short*)((char*)d_ws + 2080);       // 737280 bf16
    unsigned short* xT = (unsigned short*)((char*)d_ws + 1476640);    // 33.55M bf16
    float* loss_out = out + (out_size - 1);
    const size_t need = 1476640ull + 67108864ull;

    mean_kernel<<<BATCH * CH, 256, 0, stream>>>(x, g);
    gate_kernel<<<1, 512, 0, stream>>>(g, gw1, gb1, gw2, gb2, coef, loss_out);

    if (ws_size >= need) {
        wtrans_kernel<<<360, 256, 0, stream>>>(ew1, ew3, ew7, ew11, wT);
        xtrans_kernel<<<BATCH * HH, 256, 0, stream>>>(x, xT);
        moe32_kernel<<<4096, 256, 0, stream>>>(xT, wT, x, eb1, eb3, eb7, eb11, coef, out);
    } else {
        conv_kernel<<<BATCH * CH * HH, 256, 0, stream>>>(x, ew1, eb1, ew3, eb3, ew7, eb7,
                                                         ew11, eb11, coef, out);
    }
}

// Round 4
// 1417.137 us; speedup vs baseline: 2.1155x; 2.1155x over previous
//
#include <hip/hip_runtime.h>
#include <hip/hip_bf16.h>
#include <math.h>

#define BATCH 8
#define CH 64
#define HH 256
#define WW 256
#define HID 512
#define NE 4

typedef short v8s __attribute__((ext_vector_type(8)));
typedef float v4f __attribute__((ext_vector_type(4)));
typedef float v16f __attribute__((ext_vector_type(16)));

static __device__ __forceinline__ unsigned short f2bf(float v) {
    __hip_bfloat16 h = __float2bfloat16(v);
    return *(unsigned short*)&h;
}

// ---------------- K1: per-(b,c) spatial mean -> g[8*64] ----------------
__global__ __launch_bounds__(256) void mean_kernel(const float* __restrict__ x,
                                                   float* __restrict__ g) {
    int bc = blockIdx.x;
    const float* p = x + (size_t)bc * (HH * WW);
    float s = 0.f;
    for (int i = threadIdx.x; i < HH * WW; i += 256) s += p[i];
    __shared__ float red[256];
    red[threadIdx.x] = s;
    __syncthreads();
    for (int off = 128; off > 0; off >>= 1) {
        if (threadIdx.x < off) red[threadIdx.x] += red[threadIdx.x + off];
        __syncthreads();
    }
    if (threadIdx.x == 0) g[bc] = red[0] * (1.0f / (HH * WW));
}

// ---------------- K2: gating MLP + softmax + top2 + coef + loss --------
__global__ __launch_bounds__(512) void gate_kernel(const float* __restrict__ g,
                                                   const float* __restrict__ gw1,
                                                   const float* __restrict__ gb1,
                                                   const float* __restrict__ gw2,
                                                   const float* __restrict__ gb2,
                                                   float* __restrict__ coef_out,
                                                   float* __restrict__ loss_out) {
    __shared__ float h[BATCH][HID];
    __shared__ float logits[BATCH][NE];
    int t = threadIdx.x;
    for (int b = 0; b < BATCH; b++) {
        float acc = gb1[t];
        for (int c = 0; c < CH; c++) acc = fmaf(g[b * CH + c], gw1[t * CH + c], acc);
        h[b][t] = fmaxf(acc, 0.f);
    }
    __syncthreads();
    if (t < BATCH * NE) {
        int b = t / NE, e = t % NE;
        float acc = gb2[e];
        for (int j = 0; j < HID; j++) acc = fmaf(h[b][j], gw2[e * HID + j], acc);
        logits[b][e] = acc;
    }
    __syncthreads();
    if (t == 0) {
        float sm[BATCH][NE];
        for (int b = 0; b < BATCH; b++) {
            float m = logits[b][0];
            for (int e = 1; e < NE; e++) m = fmaxf(m, logits[b][e]);
            float s = 0.f;
            for (int e = 0; e < NE; e++) { sm[b][e] = expf(logits[b][e] - m); s += sm[b][e]; }
            for (int e = 0; e < NE; e++) sm[b][e] /= s;
        }
        float mean = 0.f;
        for (int b = 0; b < BATCH; b++)
            for (int e = 0; e < NE; e++) mean += sm[b][e];
        mean *= 1.0f / (BATCH * NE);
        float var = 0.f;
        for (int b = 0; b < BATCH; b++)
            for (int e = 0; e < NE; e++) {
                float d = sm[b][e] - mean;
                var += d * d;
            }
        var *= 1.0f / (BATCH * NE - 1);
        *loss_out = sqrtf(var) / (mean + 1e-10f) * 0.1f;
        float coef[NE] = {0.f, 0.f, 0.f, 0.f};
        for (int b = 0; b < BATCH; b++) {
            int i0 = 0;
            for (int e = 1; e < NE; e++)
                if (sm[b][e] > sm[b][i0]) i0 = e;
            int i1 = -1;
            for (int e = 0; e < NE; e++) {
                if (e == i0) continue;
                if (i1 < 0 || sm[b][e] > sm[b][i1]) i1 = e;
            }
            float v0 = sm[b][i0], v1 = sm[b][i1];
            float be = expf(v1 - v0);
            float a0 = 1.f / (1.f + be);
            float a1 = be / (1.f + be);
            coef[i0] += a0;
            coef[i1] += a1;
        }
        for (int e = 0; e < NE; e++) coef_out[e] = coef[e];
    }
}

// ---------------- K3a: weights OIHW fp32 -> wT bf16, COALESCED layout --
// New per-tap layout (4096 shorts = 8192 B per tap, tap-major unchanged):
//   [nt(2)][kc(4)][lane(64)][8 shorts]   lane = kh*32 + n
// holds w[co = nt*32+n][ci = kc*16 + kh*8 + j], j=0..7 — exactly the
// B-fragment lane l consumes for MFMA chunk kc, n-tile nt. A wave's load
// for chunk (nt,kc) is base + l*16: 64 lanes x 16 B CONTIGUOUS (8 cache
// lines/instr vs 32 with the old [co][ci] layout).
__global__ __launch_bounds__(256) void wtrans_kernel(const float* __restrict__ ew1,
                                                     const float* __restrict__ ew3,
                                                     const float* __restrict__ ew7,
                                                     const float* __restrict__ ew11,
                                                     unsigned short* __restrict__ wT) {
    int gid = blockIdx.x * 256 + threadIdx.x;  // < 180*512 = 92160
    int tapg = gid >> 9;
    int rem = gid & 511;
    int co = rem >> 3, kg = rem & 7;
    const float* src;
    int k, tap, dstbase;
    if (tapg < 1) { src = ew1; k = 1; tap = tapg; dstbase = 0; }
    else if (tapg < 10) { src = ew3; k = 3; tap = tapg - 1; dstbase = 1 * 4096; }
    else if (tapg < 59) { src = ew7; k = 7; tap = tapg - 10; dstbase = 10 * 4096; }
    else { src = ew11; k = 11; tap = tapg - 59; dstbase = 59 * 4096; }
    int ky = tap / k, kx = tap - ky * k;
    unsigned short o[8];
#pragma unroll
    for (int j = 0; j < 8; j++) {
        int ci = kg * 8 + j;
        o[j] = f2bf(src[((co * 64 + ci) * k + ky) * k + kx]);
    }
    int nt = co >> 5, nn = co & 31, kc = kg >> 1, khp = kg & 1;
    *(v8s*)(wT + (size_t)dstbase + (size_t)tap * 4096 +
            ((nt * 4 + kc) * 64 + khp * 32 + nn) * 8) = *(v8s*)o;
}

// ---------------- K3b: x NCHW fp32 -> xT[b][y][x][ci] bf16 -------------
#define XP 258
__global__ __launch_bounds__(256) void xtrans_kernel(const float* __restrict__ x,
                                                     unsigned short* __restrict__ xT) {
    __shared__ unsigned short t[64 * XP];
    int blk = blockIdx.x;  // b*256 + y
    int b = blk >> 8, y = blk & 255;
    int tid = threadIdx.x;
    for (int ci = 0; ci < 64; ci++) {
        float v = x[((size_t)(b * 64 + ci)) * 65536 + (size_t)y * 256 + tid];
        t[ci * XP + tid] = f2bf(v);
    }
    __syncthreads();
    unsigned short* dst = xT + (size_t)blk * 256 * 64;
    for (int c = tid; c < 2048; c += 256) {
        int xx = c >> 3, kg = c & 7;
        unsigned short o[8];
#pragma unroll
        for (int j = 0; j < 8; j++) o[j] = t[(kg * 8 + j) * XP + xx];
        *(v8s*)(dst + (size_t)xx * 64 + kg * 8) = *(v8s*)o;
    }
}

// ---------------- K4: 32x32x16 MFMA expert-sequential fused conv -------
// block = (b, ytile16, xtile8): 16x8 px, 64 co. 4 waves; wave w = rows
// [w*4, w*4+4) x 8 cols = 32 px (MFMA m), all 64 co = 2 n-tiles.
// LDS halo: 26 rows x 18 cols x 64 ci bf16 = 59904 B, 128 B/px, 3-bit XOR
// swizzle: 16B chunk c of pixel px stored at quad c ^ (px&7).
//
// R4 CHANGE: coalesced B-loads (wT layout transposed, see wtrans) — the
// old per-lane stride-128B pattern fragmented every B instruction into 32
// L1 line-transactions (~2048/tap/CU, the hidden serial resource). Now
// each B instruction is 1 KB contiguous (8 lines). Tap loop flattened to
// a single software-pipelined pair-loop (1-tap lookahead covers the old
// per-dy prologue stalls; dx-wrap tracked with a uniform counter).
__device__ __forceinline__ v16f mfma32(v8s a, v8s b, v16f c) {
    return __builtin_amdgcn_mfma_f32_32x32x16_bf16(a, b, c, 0, 0, 0);
}

// A-fragment load: pixel px, 4 k-slices. addr = px*128 + ((khx^q4)^(kc<<5))
#define LDA(A, sxb, pxv, khx)                                   \
    {                                                           \
        int _px = (pxv);                                        \
        const char* _ap = (sxb) + _px * 128;                    \
        int _o0 = (khx) ^ ((_px & 7) << 4);                     \
        A[0] = *(const v8s*)(_ap + _o0);                        \
        A[1] = *(const v8s*)(_ap + (_o0 ^ 32));                 \
        A[2] = *(const v8s*)(_ap + (_o0 ^ 64));                 \
        A[3] = *(const v8s*)(_ap + (_o0 ^ 96));                 \
    }

// B-fragment load: one tap (8192 B) at wp; wp already includes lane*16.
// B[kc] = nt0 chunk kc, B[4+kc] = nt1 chunk kc. Contiguous per instr.
#define LDB(B, wp)                                              \
    {                                                           \
        const char* _wp = (wp);                                 \
        B[0] = *(const v8s*)(_wp);                              \
        B[1] = *(const v8s*)(_wp + 1024);                       \
        B[2] = *(const v8s*)(_wp + 2048);                       \
        B[3] = *(const v8s*)(_wp + 3072);                       \
        B[4] = *(const v8s*)(_wp + 4096);                       \
        B[5] = *(const v8s*)(_wp + 5120);                       \
        B[6] = *(const v8s*)(_wp + 6144);                       \
        B[7] = *(const v8s*)(_wp + 7168);                       \
    }

#define MM(A, B)                                                \
    {                                                           \
        a0 = mfma32(A[0], B[0], a0);                            \
        a1 = mfma32(A[0], B[4], a1);                            \
        a0 = mfma32(A[1], B[1], a0);                            \
        a1 = mfma32(A[1], B[5], a1);                            \
        a0 = mfma32(A[2], B[2], a0);                            \
        a1 = mfma32(A[2], B[6], a1);                            \
        a0 = mfma32(A[3], B[3], a0);                            \
        a1 = mfma32(A[3], B[7], a1);                            \
    }

#define ADV()                                                   \
    {                                                           \
        dxc++; px++;                                            \
        if (dxc == KS) { dxc = 0; px += 18 - KS; }              \
    }

template <int KS, int OFF, int CIDX>
__device__ __forceinline__ void expert_pass(const unsigned short* sx,
                                            const unsigned short* wTe,
                                            const float* __restrict__ eb,
                                            const float* __restrict__ coef,
                                            int p00, int khx, int n, int l16,
                                            v16f& mix0, v16f& mix1) {
    v16f a0 = {};
    v16f a1 = {};
    const char* sxb = (const char*)sx;
    const char* wp = (const char*)wTe + l16;  // advances 8192 B per tap
    int px = p00 + OFF * 19;                  // halo px of tap (dy=0,dx=0)
    int dxc = 0;
    v8s A0[4], A1[4], B0[8], B1[8];
    LDA(A0, sxb, px, khx);
    LDB(B0, wp);
#pragma unroll 1
    for (int i = 0; i < (KS * KS - 1) / 2; ++i) {
        ADV();
        LDA(A1, sxb, px, khx);
        LDB(B1, wp + 8192);
        MM(A0, B0);
        ADV();
        LDA(A0, sxb, px, khx);
        LDB(B0, wp + 16384);
        MM(A1, B1);
        wp += 16384;
    }
    MM(A0, B0);  // last tap
    // fold this expert into the mix: mix += coef * sigmoid(acc + bias)
    float ce = coef[CIDX];
    float b0v = eb[n];
    float b1v = eb[32 + n];
#pragma unroll
    for (int r = 0; r < 16; ++r) {
        float z0 = a0[r] + b0v;
        float z1 = a1[r] + b1v;
        mix0[r] = fmaf(ce, 1.f / (1.f + __expf(-z0)), mix0[r]);
        mix1[r] = fmaf(ce, 1.f / (1.f + __expf(-z1)), mix1[r]);
    }
}

__global__ __launch_bounds__(256, 2) void moe32_kernel(
        const unsigned short* __restrict__ xT, const unsigned short* __restrict__ wT,
        const float* __restrict__ x,
        const float* __restrict__ eb1, const float* __restrict__ eb3,
        const float* __restrict__ eb7, const float* __restrict__ eb11,
        const float* __restrict__ coef, float* __restrict__ out) {
    __shared__ unsigned short sx[26 * 18 * 64];  // 59904 B
    int blk = blockIdx.x;
    int xt = blk & 31, yt = (blk >> 5) & 15, b = blk >> 9;
    int x0 = xt * 8, y0 = yt * 16;
    int tid = threadIdx.x;

    // ---- stage swizzled halo: chunk c of px stored at quad c ^ (px&7) ----
    for (int i = tid; i < 3744; i += 256) {
        int hrow = i / 144;
        int rem = i - hrow * 144;
        int hcol = rem >> 3, c = rem & 7;
        int px = hrow * 18 + hcol;
        int gy = y0 + hrow - 5, gx = x0 + hcol - 5;
        v8s v = {0, 0, 0, 0, 0, 0, 0, 0};
        if ((unsigned)gy < 256u && (unsigned)gx < 256u)
            v = *(const v8s*)(xT + (((size_t)(b * 256 + gy) * 256 + gx) * 64 + c * 8));
        int cs = c ^ (px & 7);
        *(v8s*)(sx + px * 64 + cs * 8) = v;
    }
    __syncthreads();

    int lane = tid & 63, w = tid >> 6;
    int kh = lane >> 5, n = lane & 31;
    int prow = (lane & 31) >> 3, pcol = lane & 7;
    int p00 = (w * 4 + prow) * 18 + pcol;  // halo px of this lane's pixel at tap origin
    int khx = kh << 4;
    int l16 = lane << 4;  // byte offset of this lane's B chunk within a (nt,kc) slab

    v16f mix0 = {};
    v16f mix1 = {};

    const unsigned short* wT1 = wT;
    const unsigned short* wT3 = wT + 4096;
    const unsigned short* wT7 = wT + 10 * 4096;
    const unsigned short* wT11 = wT + 59 * 4096;

    expert_pass<11, 0, 3>(sx, wT11, eb11, coef, p00, khx, n, l16, mix0, mix1);
    expert_pass<7, 2, 2>(sx, wT7, eb7, coef, p00, khx, n, l16, mix0, mix1);
    expert_pass<3, 4, 1>(sx, wT3, eb3, coef, p00, khx, n, l16, mix0, mix1);
    expert_pass<1, 5, 0>(sx, wT1, eb1, coef, p00, khx, n, l16, mix0, mix1);

    // ---- final: out = x * mix ----
    size_t pb0 = ((size_t)(b * 64 + n)) * 65536;
    size_t pb1 = ((size_t)(b * 64 + 32 + n)) * 65536;
    int yb = y0 + w * 4, xb = x0 + kh * 4;
#pragma unroll
    for (int g = 0; g < 4; ++g) {
        size_t off = (size_t)(yb + g) * 256 + xb;
        v4f xv0 = *(const v4f*)(x + pb0 + off);
        v4f xv1 = *(const v4f*)(x + pb1 + off);
        v4f o0, o1;
#pragma unroll
        for (int r = 0; r < 4; ++r) {
            o0[r] = xv0[r] * mix0[g * 4 + r];
            o1[r] = xv1[r] * mix1[g * 4 + r];
        }
        *(v4f*)(out + pb0 + off) = o0;
        *(v4f*)(out + pb1 + off) = o1;
    }
}

// ---------------- fallback direct conv (R1, verified) ------------------
__global__ __launch_bounds__(256) void conv_kernel(const float* __restrict__ x,
                                                   const float* __restrict__ ew1,
                                                   const float* __restrict__ eb1,
                                                   const float* __restrict__ ew3,
                                                   const float* __restrict__ eb3,
                                                   const float* __restrict__ ew7,
                                                   const float* __restrict__ eb7,
                                                   const float* __restrict__ ew11,
                                                   const float* __restrict__ eb11,
                                                   const float* __restrict__ coef,
                                                   float* __restrict__ out) {
    int blk = blockIdx.x;
    int y = blk & (HH - 1);
    int c = (blk >> 8) & (CH - 1);
    int b = blk >> 14;
    int xi = threadIdx.x;
    const size_t plane = (size_t)HH * WW;
    float a0 = 0.f, a1 = 0.f, a2 = 0.f, a3 = 0.f;
    for (int dy = 0; dy < 11; dy++) {
        int yy = y + dy - 5;
        if (yy < 0 || yy >= HH) continue;
        bool in7y = (dy >= 2 && dy <= 8);
        bool in3y = (dy >= 4 && dy <= 6);
        bool in1y = (dy == 5);
        for (int ci = 0; ci < CH; ci++) {
            const float* xrow = x + ((size_t)(b * CH + ci)) * plane + (size_t)yy * WW;
            const float* w11row = ew11 + (((c * CH + ci) * 11 + dy) * 11);
            const float* w7row = in7y ? (ew7 + (((c * CH + ci) * 7 + (dy - 2)) * 7)) : ew7;
            const float* w3row = in3y ? (ew3 + (((c * CH + ci) * 3 + (dy - 4)) * 3)) : ew3;
            float w1v = in1y ? ew1[c * CH + ci] : 0.f;
#pragma unroll
            for (int dx = 0; dx < 11; dx++) {
                int xc = xi + dx - 5;
                float xv = (xc >= 0 && xc < WW) ? xrow[xc] : 0.f;
                a3 = fmaf(w11row[dx], xv, a3);
                if (dx >= 2 && dx <= 8) { if (in7y) a2 = fmaf(w7row[dx - 2], xv, a2); }
                if (dx >= 4 && dx <= 6) { if (in3y) a1 = fmaf(w3row[dx - 4], xv, a1); }
                if (dx == 5) { if (in1y) a0 = fmaf(w1v, xv, a0); }
            }
        }
    }
    a0 += eb1[c]; a1 += eb3[c]; a2 += eb7[c]; a3 += eb11[c];
    float s0 = 1.f / (1.f + expf(-a0));
    float s1 = 1.f / (1.f + expf(-a1));
    float s2 = 1.f / (1.f + expf(-a2));
    float s3 = 1.f / (1.f + expf(-a3));
    float mix = coef[0] * s0 + coef[1] * s1 + coef[2] * s2 + coef[3] * s3;
    size_t idx = ((size_t)(b * CH + c)) * plane + (size_t)y * WW + xi;
    out[idx] = x[idx] * mix;
}

extern "C" void kernel_launch(void* const* d_in, const int* in_sizes, int n_in,
                              void* d_out, int out_size, void* d_ws, size_t ws_size,
                              hipStream_t stream) {
    const float* x = (const float*)d_in[0];
    const float* gw1 = (const float*)d_in[1];
    const float* gb1 = (const float*)d_in[2];
    const float* gw2 = (const float*)d_in[3];
    const float* gb2 = (const float*)d_in[4];
    const float* ew1 = (const float*)d_in[5];
    const float* eb1 = (const float*)d_in[6];
    const float* ew3 = (const float*)d_in[7];
    const float* eb3 = (const float*)d_in[8];
    const float* ew7 = (const float*)d_in[9];
    const float* eb7 = (const float*)d_in[10];
    const float* ew11 = (const float*)d_in[11];
    const float* eb11 = (const float*)d_in[12];

    float* out = (float*)d_out;
    float* wsf = (float*)d_ws;
    float* g = wsf;                                // 512 floats
    float* coef = wsf + 512;                       // 4 floats (+pad to 520)
    unsigned short* wT = (unsigned short*)((char*)d_ws + 2080);       // 737280 bf16
    unsigned short* xT = (unsigned short*)((char*)d_ws + 1476640);    // 33.55M bf16
    float* loss_out = out + (out_size - 1);
    const size_t need = 1476640ull + 67108864ull;

    mean_kernel<<<BATCH * CH, 256, 0, stream>>>(x, g);
    gate_kernel<<<1, 512, 0, stream>>>(g, gw1, gb1, gw2, gb2, coef, loss_out);

    if (ws_size >= need) {
        wtrans_kernel<<<360, 256, 0, stream>>>(ew1, ew3, ew7, ew11, wT);
        xtrans_kernel<<<BATCH * HH, 256, 0, stream>>>(x, xT);
        moe32_kernel<<<4096, 256, 0, stream>>>(xT, wT, x, eb1, eb3, eb7, eb11, coef, out);
    } else {
        conv_kernel<<<BATCH * CH * HH, 256, 0, stream>>>(x, ew1, eb1, ew3, eb3, ew7, eb7,
                                                         ew11, eb11, coef, out);
    }
}

// Round 5
// 1366.591 us; speedup vs baseline: 2.1938x; 1.0370x over previous
//
#include <hip/hip_runtime.h>
#include <hip/hip_bf16.h>
#include <math.h>

#define BATCH 8
#define CH 64
#define HH 256
#define WW 256
#define HID 512
#define NE 4

typedef short v8s __attribute__((ext_vector_type(8)));
typedef float v4f __attribute__((ext_vector_type(4)));
typedef float v16f __attribute__((ext_vector_type(16)));

static __device__ __forceinline__ unsigned short f2bf(float v) {
    __hip_bfloat16 h = __float2bfloat16(v);
    return *(unsigned short*)&h;
}

// ---------------- K1: per-(b,c) spatial mean -> g[8*64] ----------------
__global__ __launch_bounds__(256) void mean_kernel(const float* __restrict__ x,
                                                   float* __restrict__ g) {
    int bc = blockIdx.x;
    const float* p = x + (size_t)bc * (HH * WW);
    float s = 0.f;
    for (int i = threadIdx.x; i < HH * WW; i += 256) s += p[i];
    __shared__ float red[256];
    red[threadIdx.x] = s;
    __syncthreads();
    for (int off = 128; off > 0; off >>= 1) {
        if (threadIdx.x < off) red[threadIdx.x] += red[threadIdx.x + off];
        __syncthreads();
    }
    if (threadIdx.x == 0) g[bc] = red[0] * (1.0f / (HH * WW));
}

// ---------------- K2: gating MLP + softmax + top2 + coef + loss --------
__global__ __launch_bounds__(512) void gate_kernel(const float* __restrict__ g,
                                                   const float* __restrict__ gw1,
                                                   const float* __restrict__ gb1,
                                                   const float* __restrict__ gw2,
                                                   const float* __restrict__ gb2,
                                                   float* __restrict__ coef_out,
                                                   float* __restrict__ loss_out) {
    __shared__ float h[BATCH][HID];
    __shared__ float logits[BATCH][NE];
    int t = threadIdx.x;
    for (int b = 0; b < BATCH; b++) {
        float acc = gb1[t];
        for (int c = 0; c < CH; c++) acc = fmaf(g[b * CH + c], gw1[t * CH + c], acc);
        h[b][t] = fmaxf(acc, 0.f);
    }
    __syncthreads();
    if (t < BATCH * NE) {
        int b = t / NE, e = t % NE;
        float acc = gb2[e];
        for (int j = 0; j < HID; j++) acc = fmaf(h[b][j], gw2[e * HID + j], acc);
        logits[b][e] = acc;
    }
    __syncthreads();
    if (t == 0) {
        float sm[BATCH][NE];
        for (int b = 0; b < BATCH; b++) {
            float m = logits[b][0];
            for (int e = 1; e < NE; e++) m = fmaxf(m, logits[b][e]);
            float s = 0.f;
            for (int e = 0; e < NE; e++) { sm[b][e] = expf(logits[b][e] - m); s += sm[b][e]; }
            for (int e = 0; e < NE; e++) sm[b][e] /= s;
        }
        float mean = 0.f;
        for (int b = 0; b < BATCH; b++)
            for (int e = 0; e < NE; e++) mean += sm[b][e];
        mean *= 1.0f / (BATCH * NE);
        float var = 0.f;
        for (int b = 0; b < BATCH; b++)
            for (int e = 0; e < NE; e++) {
                float d = sm[b][e] - mean;
                var += d * d;
            }
        var *= 1.0f / (BATCH * NE - 1);
        *loss_out = sqrtf(var) / (mean + 1e-10f) * 0.1f;
        float coef[NE] = {0.f, 0.f, 0.f, 0.f};
        for (int b = 0; b < BATCH; b++) {
            int i0 = 0;
            for (int e = 1; e < NE; e++)
                if (sm[b][e] > sm[b][i0]) i0 = e;
            int i1 = -1;
            for (int e = 0; e < NE; e++) {
                if (e == i0) continue;
                if (i1 < 0 || sm[b][e] > sm[b][i1]) i1 = e;
            }
            float v0 = sm[b][i0], v1 = sm[b][i1];
            float be = expf(v1 - v0);
            float a0 = 1.f / (1.f + be);
            float a1 = be / (1.f + be);
            coef[i0] += a0;
            coef[i1] += a1;
        }
        for (int e = 0; e < NE; e++) coef_out[e] = coef[e];
    }
}

// ---------------- K3a: weights OIHW fp32 -> wT bf16, COALESCED layout --
// Per-tap layout (4096 shorts = 8192 B per tap, tap-major):
//   [nt(2)][kc(4)][lane(64)][8 shorts]   lane = kh*32 + n
// holds w[co = nt*32+n][ci = kc*16 + kh*8 + j], j=0..7 — exactly the
// B-fragment lane l consumes for MFMA chunk kc, n-tile nt. A wave's load
// for chunk (nt,kc) is base + l*16: 64 lanes x 16 B CONTIGUOUS.
__global__ __launch_bounds__(256) void wtrans_kernel(const float* __restrict__ ew1,
                                                     const float* __restrict__ ew3,
                                                     const float* __restrict__ ew7,
                                                     const float* __restrict__ ew11,
                                                     unsigned short* __restrict__ wT) {
    int gid = blockIdx.x * 256 + threadIdx.x;  // < 180*512 = 92160
    int tapg = gid >> 9;
    int rem = gid & 511;
    int co = rem >> 3, kg = rem & 7;
    const float* src;
    int k, tap, dstbase;
    if (tapg < 1) { src = ew1; k = 1; tap = tapg; dstbase = 0; }
    else if (tapg < 10) { src = ew3; k = 3; tap = tapg - 1; dstbase = 1 * 4096; }
    else if (tapg < 59) { src = ew7; k = 7; tap = tapg - 10; dstbase = 10 * 4096; }
    else { src = ew11; k = 11; tap = tapg - 59; dstbase = 59 * 4096; }
    int ky = tap / k, kx = tap - ky * k;
    unsigned short o[8];
#pragma unroll
    for (int j = 0; j < 8; j++) {
        int ci = kg * 8 + j;
        o[j] = f2bf(src[((co * 64 + ci) * k + ky) * k + kx]);
    }
    int nt = co >> 5, nn = co & 31, kc = kg >> 1, khp = kg & 1;
    *(v8s*)(wT + (size_t)dstbase + (size_t)tap * 4096 +
            ((nt * 4 + kc) * 64 + khp * 32 + nn) * 8) = *(v8s*)o;
}

// ---------------- K3b: x NCHW fp32 -> xT[b][y][x][ci] bf16 -------------
#define XP 258
__global__ __launch_bounds__(256) void xtrans_kernel(const float* __restrict__ x,
                                                     unsigned short* __restrict__ xT) {
    __shared__ unsigned short t[64 * XP];
    int blk = blockIdx.x;  // b*256 + y
    int b = blk >> 8, y = blk & 255;
    int tid = threadIdx.x;
    for (int ci = 0; ci < 64; ci++) {
        float v = x[((size_t)(b * 64 + ci)) * 65536 + (size_t)y * 256 + tid];
        t[ci * XP + tid] = f2bf(v);
    }
    __syncthreads();
    unsigned short* dst = xT + (size_t)blk * 256 * 64;
    for (int c = tid; c < 2048; c += 256) {
        int xx = c >> 3, kg = c & 7;
        unsigned short o[8];
#pragma unroll
        for (int j = 0; j < 8; j++) o[j] = t[(kg * 8 + j) * XP + xx];
        *(v8s*)(dst + (size_t)xx * 64 + kg * 8) = *(v8s*)o;
    }
}

// ---------------- K4: 32x32x16 MFMA expert-sequential fused conv -------
// block = (b, ytile16, xtile8): 16x8 px, 64 co. 4 waves; wave w = rows
// [w*4, w*4+4) x 8 cols = 32 px (MFMA m), all 64 co = 2 n-tiles.
// LDS halo: 26 rows x 18 cols x 64 ci bf16 = 59904 B, 128 B/px, 3-bit XOR
// swizzle: 16B chunk c of pixel px stored at quad c ^ (px&7).
//
// R5 CHANGE: depth-2 prefetch. R4's pair-loop issued each tap's loads
// only ~129 cy (16 MFMA) before use, short of the ~200-225 cy L2-hit
// latency of the weight stream -> ~100 cy stall/tap/wave (MfmaUtil 31%).
// Now single-tap steps with A and B prefetched 2 taps ahead into 3
// rotating register sets (period-3, loop unrolled x3 so all indices are
// static). Cover = ~256 cy/wave. s_setprio(1) wraps each 8-MFMA cluster
// (T5: the 2 waves/SIMD now alternate load-issue vs MFMA roles).
__device__ __forceinline__ v16f mfma32(v8s a, v8s b, v16f c) {
    return __builtin_amdgcn_mfma_f32_32x32x16_bf16(a, b, c, 0, 0, 0);
}

// A-fragment load: pixel px, 4 k-slices. addr = px*128 + ((khx^q4)^(kc<<5))
#define LDA(A, sxb, pxv, khx)                                   \
    {                                                           \
        int _px = (pxv);                                        \
        const char* _ap = (sxb) + _px * 128;                    \
        int _o0 = (khx) ^ ((_px & 7) << 4);                     \
        A[0] = *(const v8s*)(_ap + _o0);                        \
        A[1] = *(const v8s*)(_ap + (_o0 ^ 32));                 \
        A[2] = *(const v8s*)(_ap + (_o0 ^ 64));                 \
        A[3] = *(const v8s*)(_ap + (_o0 ^ 96));                 \
    }

// B-fragment load: one tap (8192 B) at wp; wp already includes lane*16.
#define LDB(B, wp)                                              \
    {                                                           \
        const char* _wp = (wp);                                 \
        B[0] = *(const v8s*)(_wp);                              \
        B[1] = *(const v8s*)(_wp + 1024);                       \
        B[2] = *(const v8s*)(_wp + 2048);                       \
        B[3] = *(const v8s*)(_wp + 3072);                       \
        B[4] = *(const v8s*)(_wp + 4096);                       \
        B[5] = *(const v8s*)(_wp + 5120);                       \
        B[6] = *(const v8s*)(_wp + 6144);                       \
        B[7] = *(const v8s*)(_wp + 7168);                       \
    }

#define MM(A, B)                                                \
    {                                                           \
        __builtin_amdgcn_s_setprio(1);                          \
        a0 = mfma32(A[0], B[0], a0);                            \
        a1 = mfma32(A[0], B[4], a1);                            \
        a0 = mfma32(A[1], B[1], a0);                            \
        a1 = mfma32(A[1], B[5], a1);                            \
        a0 = mfma32(A[2], B[2], a0);                            \
        a1 = mfma32(A[2], B[6], a1);                            \
        a0 = mfma32(A[3], B[3], a0);                            \
        a1 = mfma32(A[3], B[7], a1);                            \
        __builtin_amdgcn_s_setprio(0);                          \
    }

// advance the load cursor by one tap (px walks the halo, wp the wT stream)
#define ADV()                                                   \
    {                                                           \
        dxc++; px++; wp += 8192;                                \
        if (dxc == KS) { dxc = 0; px += 18 - KS; }              \
    }

template <int KS, int OFF, int CIDX>
__device__ __forceinline__ void expert_pass(const unsigned short* sx,
                                            const unsigned short* wTe,
                                            const float* __restrict__ eb,
                                            const float* __restrict__ coef,
                                            int p00, int khx, int n, int l16,
                                            v16f& mix0, v16f& mix1) {
    v16f a0 = {};
    v16f a1 = {};
    const char* sxb = (const char*)sx;
    const char* wp = (const char*)wTe + l16;  // load cursor (byte ptr)
    int px = p00 + OFF * 19;                  // load cursor halo pixel
    int dxc = 0;
    v8s A0[4], A1[4], A2[4], B0[8], B1[8], B2[8];
    if constexpr (KS == 1) {
        LDA(A0, sxb, px, khx);
        LDB(B0, wp);
        MM(A0, B0);
    } else {
        constexpr int N = KS * KS;
        // prologue: taps 0,1 into sets 0,1; cursor ends at tap 2
        LDA(A0, sxb, px, khx); LDB(B0, wp); ADV();
        LDA(A1, sxb, px, khx); LDB(B1, wp); ADV();
        // body: steps t = 0..N-3; step t loads tap t+2 (set (t+2)%3),
        // consumes tap t (set t%3). Unrolled x3 -> all indices static.
#pragma unroll 1
        for (int m = 0; m < (N - 2) / 3; ++m) {
            LDA(A2, sxb, px, khx); LDB(B2, wp); ADV();
            MM(A0, B0);
            LDA(A0, sxb, px, khx); LDB(B0, wp); ADV();
            MM(A1, B1);
            LDA(A1, sxb, px, khx); LDB(B1, wp); ADV();
            MM(A2, B2);
        }
        constexpr int rem = (N - 2) % 3;  // 2 for KS=11,7; 1 for KS=3
        if constexpr (rem == 1) {
            LDA(A2, sxb, px, khx); LDB(B2, wp); ADV();
            MM(A0, B0);
            MM(A1, B1);
            MM(A2, B2);
        } else if constexpr (rem == 2) {
            LDA(A2, sxb, px, khx); LDB(B2, wp); ADV();
            MM(A0, B0);
            LDA(A0, sxb, px, khx); LDB(B0, wp); ADV();
            MM(A1, B1);
            MM(A2, B2);
            MM(A0, B0);
        }
    }
    // fold this expert into the mix: mix += coef * sigmoid(acc + bias)
    float ce = coef[CIDX];
    float b0v = eb[n];
    float b1v = eb[32 + n];
#pragma unroll
    for (int r = 0; r < 16; ++r) {
        float z0 = a0[r] + b0v;
        float z1 = a1[r] + b1v;
        mix0[r] = fmaf(ce, 1.f / (1.f + __expf(-z0)), mix0[r]);
        mix1[r] = fmaf(ce, 1.f / (1.f + __expf(-z1)), mix1[r]);
    }
}

__global__ __launch_bounds__(256, 2) void moe32_kernel(
        const unsigned short* __restrict__ xT, const unsigned short* __restrict__ wT,
        const float* __restrict__ x,
        const float* __restrict__ eb1, const float* __restrict__ eb3,
        const float* __restrict__ eb7, const float* __restrict__ eb11,
        const float* __restrict__ coef, float* __restrict__ out) {
    __shared__ unsigned short sx[26 * 18 * 64];  // 59904 B
    int blk = blockIdx.x;
    int xt = blk & 31, yt = (blk >> 5) & 15, b = blk >> 9;
    int x0 = xt * 8, y0 = yt * 16;
    int tid = threadIdx.x;

    // ---- stage swizzled halo: chunk c of px stored at quad c ^ (px&7) ----
    for (int i = tid; i < 3744; i += 256) {
        int hrow = i / 144;
        int rem = i - hrow * 144;
        int hcol = rem >> 3, c = rem & 7;
        int px = hrow * 18 + hcol;
        int gy = y0 + hrow - 5, gx = x0 + hcol - 5;
        v8s v = {0, 0, 0, 0, 0, 0, 0, 0};
        if ((unsigned)gy < 256u && (unsigned)gx < 256u)
            v = *(const v8s*)(xT + (((size_t)(b * 256 + gy) * 256 + gx) * 64 + c * 8));
        int cs = c ^ (px & 7);
        *(v8s*)(sx + px * 64 + cs * 8) = v;
    }
    __syncthreads();

    int lane = tid & 63, w = tid >> 6;
    int kh = lane >> 5, n = lane & 31;
    int prow = (lane & 31) >> 3, pcol = lane & 7;
    int p00 = (w * 4 + prow) * 18 + pcol;  // halo px of this lane's pixel at tap origin
    int khx = kh << 4;
    int l16 = lane << 4;  // byte offset of this lane's B chunk within a (nt,kc) slab

    v16f mix0 = {};
    v16f mix1 = {};

    const unsigned short* wT1 = wT;
    const unsigned short* wT3 = wT + 4096;
    const unsigned short* wT7 = wT + 10 * 4096;
    const unsigned short* wT11 = wT + 59 * 4096;

    expert_pass<11, 0, 3>(sx, wT11, eb11, coef, p00, khx, n, l16, mix0, mix1);
    expert_pass<7, 2, 2>(sx, wT7, eb7, coef, p00, khx, n, l16, mix0, mix1);
    expert_pass<3, 4, 1>(sx, wT3, eb3, coef, p00, khx, n, l16, mix0, mix1);
    expert_pass<1, 5, 0>(sx, wT1, eb1, coef, p00, khx, n, l16, mix0, mix1);

    // ---- final: out = x * mix ----
    size_t pb0 = ((size_t)(b * 64 + n)) * 65536;
    size_t pb1 = ((size_t)(b * 64 + 32 + n)) * 65536;
    int yb = y0 + w * 4, xb = x0 + kh * 4;
#pragma unroll
    for (int g = 0; g < 4; ++g) {
        size_t off = (size_t)(yb + g) * 256 + xb;
        v4f xv0 = *(const v4f*)(x + pb0 + off);
        v4f xv1 = *(const v4f*)(x + pb1 + off);
        v4f o0, o1;
#pragma unroll
        for (int r = 0; r < 4; ++r) {
            o0[r] = xv0[r] * mix0[g * 4 + r];
            o1[r] = xv1[r] * mix1[g * 4 + r];
        }
        *(v4f*)(out + pb0 + off) = o0;
        *(v4f*)(out + pb1 + off) = o1;
    }
}

// ---------------- fallback direct conv (R1, verified) ------------------
__global__ __launch_bounds__(256) void conv_kernel(const float* __restrict__ x,
                                                   const float* __restrict__ ew1,
                                                   const float* __restrict__ eb1,
                                                   const float* __restrict__ ew3,
                                                   const float* __restrict__ eb3,
                                                   const float* __restrict__ ew7,
                                                   const float* __restrict__ eb7,
                                                   const float* __restrict__ ew11,
                                                   const float* __restrict__ eb11,
                                                   const float* __restrict__ coef,
                                                   float* __restrict__ out) {
    int blk = blockIdx.x;
    int y = blk & (HH - 1);
    int c = (blk >> 8) & (CH - 1);
    int b = blk >> 14;
    int xi = threadIdx.x;
    const size_t plane = (size_t)HH * WW;
    float a0 = 0.f, a1 = 0.f, a2 = 0.f, a3 = 0.f;
    for (int dy = 0; dy < 11; dy++) {
        int yy = y + dy - 5;
        if (yy < 0 || yy >= HH) continue;
        bool in7y = (dy >= 2 && dy <= 8);
        bool in3y = (dy >= 4 && dy <= 6);
        bool in1y = (dy == 5);
        for (int ci = 0; ci < CH; ci++) {
            const float* xrow = x + ((size_t)(b * CH + ci)) * plane + (size_t)yy * WW;
            const float* w11row = ew11 + (((c * CH + ci) * 11 + dy) * 11);
            const float* w7row = in7y ? (ew7 + (((c * CH + ci) * 7 + (dy - 2)) * 7)) : ew7;
            const float* w3row = in3y ? (ew3 + (((c * CH + ci) * 3 + (dy - 4)) * 3)) : ew3;
            float w1v = in1y ? ew1[c * CH + ci] : 0.f;
#pragma unroll
            for (int dx = 0; dx < 11; dx++) {
                int xc = xi + dx - 5;
                float xv = (xc >= 0 && xc < WW) ? xrow[xc] : 0.f;
                a3 = fmaf(w11row[dx], xv, a3);
                if (dx >= 2 && dx <= 8) { if (in7y) a2 = fmaf(w7row[dx - 2], xv, a2); }
                if (dx >= 4 && dx <= 6) { if (in3y) a1 = fmaf(w3row[dx - 4], xv, a1); }
                if (dx == 5) { if (in1y) a0 = fmaf(w1v, xv, a0); }
            }
        }
    }
    a0 += eb1[c]; a1 += eb3[c]; a2 += eb7[c]; a3 += eb11[c];
    float s0 = 1.f / (1.f + expf(-a0));
    float s1 = 1.f / (1.f + expf(-a1));
    float s2 = 1.f / (1.f + expf(-a2));
    float s3 = 1.f / (1.f + expf(-a3));
    float mix = coef[0] * s0 + coef[1] * s1 + coef[2] * s2 + coef[3] * s3;
    size_t idx = ((size_t)(b * CH + c)) * plane + (size_t)y * WW + xi;
    out[idx] = x[idx] * mix;
}

extern "C" void kernel_launch(void* const* d_in, const int* in_sizes, int n_in,
                              void* d_out, int out_size, void* d_ws, size_t ws_size,
                              hipStream_t stream) {
    const float* x = (const float*)d_in[0];
    const float* gw1 = (const float*)d_in[1];
    const float* gb1 = (const float*)d_in[2];
    const float* gw2 = (const float*)d_in[3];
    const float* gb2 = (const float*)d_in[4];
    const float* ew1 = (const float*)d_in[5];
    const float* eb1 = (const float*)d_in[6];
    const float* ew3 = (const float*)d_in[7];
    const float* eb3 = (const float*)d_in[8];
    const float* ew7 = (const float*)d_in[9];
    const float* eb7 = (const float*)d_in[10];
    const float* ew11 = (const float*)d_in[11];
    const float* eb11 = (const float*)d_in[12];

    float* out = (float*)d_out;
    float* wsf = (float*)d_ws;
    float* g = wsf;                                // 512 floats
    float* coef = wsf + 512;                       // 4 floats (+pad to 520)
    unsigned short* wT = (unsigned short*)((char*)d_ws + 2080);       // 737280 bf16
    unsigned short* xT = (unsigned short*)((char*)d_ws + 1476640);    // 33.55M bf16
    float* loss_out = out + (out_size - 1);
    const size_t need = 1476640ull + 67108864ull;

    mean_kernel<<<BATCH * CH, 256, 0, stream>>>(x, g);
    gate_kernel<<<1, 512, 0, stream>>>(g, gw1, gb1, gw2, gb2, coef, loss_out);

    if (ws_size >= need) {
        wtrans_kernel<<<360, 256, 0, stream>>>(ew1, ew3, ew7, ew11, wT);
        xtrans_kernel<<<BATCH * HH, 256, 0, stream>>>(x, xT);
        moe32_kernel<<<4096, 256, 0, stream>>>(xT, wT, x, eb1, eb3, eb7, eb11, coef, out);
    } else {
        conv_kernel<<<BATCH * CH * HH, 256, 0, stream>>>(x, ew1, eb1, ew3, eb3, ew7, eb7,
                                                         ew11, eb11, coef, out);
    }
}